// Round 1
// baseline (945.287 us; speedup 1.0000x reference)
//
#include <hip/hip_runtime.h>
#include <cstdint>
#include <cstddef>

#define S_LEN 2048
#define HID   3072
#define NH    24
#define NKV   8
#define HD    128
#define ROT   96
#define OPSZ  5120   // NH*HD + 2*NKV*HD
#define NREP  3      // NH/NKV
#define SCALING 0.08838834764831845f

typedef _Float16 f16;
typedef float f32x4 __attribute__((ext_vector_type(4)));
typedef _Float16 f16x8 __attribute__((ext_vector_type(8)));
typedef _Float16 f16x4 __attribute__((ext_vector_type(4)));

// ---------------- cast fp32 -> fp16 (4 elems/thread) ----------------
__global__ void k_cast4(const float* __restrict__ in, f16* __restrict__ out, int n4) {
  int i = blockIdx.x * blockDim.x + threadIdx.x;
  if (i >= n4) return;
  float4 v = reinterpret_cast<const float4*>(in)[i];
  f16x4 o = {(f16)v.x, (f16)v.y, (f16)v.z, (f16)v.w};
  reinterpret_cast<f16x4*>(out)[i] = o;
}

// ---------------- GEMM building blocks ----------------
// Stage a 128x32 f16 tile (rows m0..m0+127, cols k0..k0+31 of G with leading dim ld)
// into LDS laid out [row][k] row-major, 32 f16 per row. 256 threads, 16B/loads.
__device__ __forceinline__ void stage16(const f16* __restrict__ G, int ld, int m0, int k0,
                                        f16* __restrict__ Ls) {
  int t = threadIdx.x;
#pragma unroll
  for (int j = 0; j < 2; ++j) {
    int lin = t + 256 * j;   // 0..511
    int row = lin >> 2;
    int seg = lin & 3;
    const int4* gp = reinterpret_cast<const int4*>(G + (size_t)(m0 + row) * ld + k0 + seg * 8);
    *reinterpret_cast<int4*>(Ls + row * 32 + seg * 8) = *gp;
  }
}

// One BK=32 step: 16 MFMAs on a 64x64 per-wave tile (4x4 of 16x16x32).
__device__ __forceinline__ void mma_tile(const f16* __restrict__ As, const f16* __restrict__ Bs,
                                         f32x4 acc[4][4], int wm, int wn, int lrow, int quad) {
  f16x8 a[4], b[4];
#pragma unroll
  for (int mi = 0; mi < 4; ++mi)
    a[mi] = *reinterpret_cast<const f16x8*>(As + (wm + mi * 16 + lrow) * 32 + quad * 8);
#pragma unroll
  for (int ni = 0; ni < 4; ++ni)
    b[ni] = *reinterpret_cast<const f16x8*>(Bs + (wn + ni * 16 + lrow) * 32 + quad * 8);
#pragma unroll
  for (int mi = 0; mi < 4; ++mi)
#pragma unroll
    for (int ni = 0; ni < 4; ++ni)
      acc[mi][ni] = __builtin_amdgcn_mfma_f32_16x16x32_f16(a[mi], b[ni], acc[mi][ni], 0, 0, 0);
}

// ---------------- QKV GEMM: C[2048,5120] = X[2048,3072] * W^T (W[5120,3072]) ----------------
__global__ __launch_bounds__(256) void k_gemm_qkv(const f16* __restrict__ A,
                                                  const f16* __restrict__ B,
                                                  f16* __restrict__ C) {
  int m0 = blockIdx.y * 128, n0 = blockIdx.x * 128;
  __shared__ __align__(16) f16 As[128 * 32];
  __shared__ __align__(16) f16 Bs[128 * 32];
  f32x4 acc[4][4] = {};
  int t = threadIdx.x, lane = t & 63, w = t >> 6;
  int wm = (w >> 1) * 64, wn = (w & 1) * 64, lrow = lane & 15, quad = lane >> 4;
  for (int kb = 0; kb < HID / 32; ++kb) {
    stage16(A, HID, m0, kb * 32, As);
    stage16(B, HID, n0, kb * 32, Bs);
    __syncthreads();
    mma_tile(As, Bs, acc, wm, wn, lrow, quad);
    __syncthreads();
  }
#pragma unroll
  for (int mi = 0; mi < 4; ++mi)
#pragma unroll
    for (int ni = 0; ni < 4; ++ni)
#pragma unroll
      for (int r = 0; r < 4; ++r) {
        int row = m0 + wm + mi * 16 + quad * 4 + r;
        int col = n0 + wn + ni * 16 + lrow;
        C[(size_t)row * OPSZ + col] = (f16)acc[mi][ni][r];
      }
}

// ---------------- out proj: Out[2048,3072] = AO[2048,3072] * Wo^T, fp32 out ----------------
__global__ __launch_bounds__(256) void k_gemm_out(const f16* __restrict__ A,
                                                  const f16* __restrict__ B,
                                                  float* __restrict__ C) {
  int m0 = blockIdx.y * 128, n0 = blockIdx.x * 128;
  __shared__ __align__(16) f16 As[128 * 32];
  __shared__ __align__(16) f16 Bs[128 * 32];
  f32x4 acc[4][4] = {};
  int t = threadIdx.x, lane = t & 63, w = t >> 6;
  int wm = (w >> 1) * 64, wn = (w & 1) * 64, lrow = lane & 15, quad = lane >> 4;
  for (int kb = 0; kb < HID / 32; ++kb) {
    stage16(A, HID, m0, kb * 32, As);
    stage16(B, HID, n0, kb * 32, Bs);
    __syncthreads();
    mma_tile(As, Bs, acc, wm, wn, lrow, quad);
    __syncthreads();
  }
#pragma unroll
  for (int mi = 0; mi < 4; ++mi)
#pragma unroll
    for (int ni = 0; ni < 4; ++ni)
#pragma unroll
      for (int r = 0; r < 4; ++r) {
        int row = m0 + wm + mi * 16 + quad * 4 + r;
        int col = n0 + wn + ni * 16 + lrow;
        C[(size_t)row * HID + col] = acc[mi][ni][r];
      }
}

// ---------------- RoPE on Q and K heads ----------------
// qkv[2048,5120] f16 -> Q[24,2048,128] f16, Kc[8,2048,128] f16
__global__ void k_rope(const f16* __restrict__ qkv, const float* __restrict__ cosd,
                       const float* __restrict__ sind, f16* __restrict__ Q,
                       f16* __restrict__ Kc) {
  int idx = blockIdx.x * 256 + threadIdx.x;  // 32*2048*128 total
  int d = idx & 127;
  int s = (idx >> 7) & (S_LEN - 1);
  int hh = idx >> 18;  // 0..31
  int srcCol = (hh < NH) ? hh * HD + d : HID + (hh - NH) * HD + d;
  float x = (float)qkv[(size_t)s * OPSZ + srcCol];
  float r;
  if (d < ROT) {
    float c = cosd[s * ROT + d], sn = sind[s * ROT + d];
    int pd = (d < 48) ? d + 48 : d - 48;
    float px = (float)qkv[(size_t)s * OPSZ + srcCol - d + pd];
    r = x * c + ((d < 48) ? -px : px) * sn;
  } else {
    r = x;
  }
  f16 o = (f16)r;
  if (hh < NH) Q[((size_t)hh * S_LEN + s) * HD + d] = o;
  else         Kc[((size_t)(hh - NH) * S_LEN + s) * HD + d] = o;
}

// ---------------- V transpose: Vt[8,128,2048] <- qkv[:, 4096 + kv*128 + d] ----------------
__global__ void k_vt(const f16* __restrict__ qkv, f16* __restrict__ Vt) {
  __shared__ f16 tile[32][33];
  int s0 = blockIdx.x * 32, d0 = blockIdx.y * 32, kv = blockIdx.z;
  int tx = threadIdx.x & 31, ty = threadIdx.x >> 5;  // 32 x 8
#pragma unroll
  for (int i = 0; i < 4; ++i)
    tile[ty + i * 8][tx] = qkv[(size_t)(s0 + ty + i * 8) * OPSZ + 4096 + kv * HD + d0 + tx];
  __syncthreads();
#pragma unroll
  for (int i = 0; i < 4; ++i)
    Vt[((size_t)kv * HD + d0 + ty + i * 8) * S_LEN + s0 + tx] = tile[tx][ty + i * 8];
}

// ---------------- scores: Sc[h,s,t] = scale * Q_h . K_kv, causal (upper = 0) ----------------
__global__ __launch_bounds__(256) void k_scores(const f16* __restrict__ Q,
                                                const f16* __restrict__ Kc,
                                                float* __restrict__ Sc) {
  int bn = blockIdx.x, bm = blockIdx.y, h = blockIdx.z;
  float* out = Sc + (size_t)h * S_LEN * S_LEN;
  int m0 = bm * 128, n0 = bn * 128;
  int t = threadIdx.x;
  if (bn > bm) {  // fully masked block: final value is exactly 0
    float4 z = {0.f, 0.f, 0.f, 0.f};
#pragma unroll
    for (int j = 0; j < 16; ++j) {
      int lin = t + 256 * j;  // 0..4095 float4 chunks
      int row = lin >> 5;
      int seg = lin & 31;
      reinterpret_cast<float4*>(out + (size_t)(m0 + row) * S_LEN + n0)[seg] = z;
    }
    return;
  }
  __shared__ __align__(16) f16 As[128 * 32];
  __shared__ __align__(16) f16 Bs[128 * 32];
  f32x4 acc[4][4] = {};
  const f16* Ah = Q + (size_t)h * S_LEN * HD;
  const f16* Bh = Kc + (size_t)(h / NREP) * S_LEN * HD;
  int lane = t & 63, w = t >> 6;
  int wm = (w >> 1) * 64, wn = (w & 1) * 64, lrow = lane & 15, quad = lane >> 4;
  for (int kb = 0; kb < HD / 32; ++kb) {
    stage16(Ah, HD, m0, kb * 32, As);
    stage16(Bh, HD, n0, kb * 32, Bs);
    __syncthreads();
    mma_tile(As, Bs, acc, wm, wn, lrow, quad);
    __syncthreads();
  }
#pragma unroll
  for (int mi = 0; mi < 4; ++mi)
#pragma unroll
    for (int ni = 0; ni < 4; ++ni)
#pragma unroll
      for (int r = 0; r < 4; ++r) {
        int row = m0 + wm + mi * 16 + quad * 4 + r;
        int col = n0 + wn + ni * 16 + lrow;
        float v = acc[mi][ni][r] * SCALING;
        if (col > row) v = 0.f;
        out[(size_t)row * S_LEN + col] = v;
      }
}

// ---------------- row softmax in place over first (r+1) elements ----------------
__global__ __launch_bounds__(256) void k_softmax(float* __restrict__ Sc) {
  int r = blockIdx.x & (S_LEN - 1);
  int h = blockIdx.x >> 11;
  float* row = Sc + ((size_t)h * S_LEN + r) * S_LEN;
  int n = r + 1;
  int t = threadIdx.x;
  float vals[8];
  int cnt = 0;
  float mx = -3.0e38f;
  for (int i = t; i < n; i += 256) {
    float v = row[i];
    vals[cnt++] = v;
    mx = fmaxf(mx, v);
  }
  __shared__ float red[4];
#pragma unroll
  for (int o = 32; o > 0; o >>= 1) mx = fmaxf(mx, __shfl_down(mx, o));
  if ((t & 63) == 0) red[t >> 6] = mx;
  __syncthreads();
  mx = fmaxf(fmaxf(red[0], red[1]), fmaxf(red[2], red[3]));
  __syncthreads();
  float sum = 0.f;
  for (int j = 0; j < cnt; ++j) {
    vals[j] = __expf(vals[j] - mx);
    sum += vals[j];
  }
#pragma unroll
  for (int o = 32; o > 0; o >>= 1) sum += __shfl_down(sum, o);
  if ((t & 63) == 0) red[t >> 6] = sum;
  __syncthreads();
  sum = red[0] + red[1] + red[2] + red[3];
  float inv = 1.0f / sum;
  cnt = 0;
  for (int i = t; i < n; i += 256) row[i] = vals[cnt++] * inv;
}

// ---------------- PV: AO[s, h*128+d] = sum_t P[h,s,t] * V[kv,t,d] ----------------
// P fp32 read from d_out attn region (staged to f16), B = Vt[kv][d][t].
__global__ __launch_bounds__(256) void k_pv(const float* __restrict__ Sc,
                                            const f16* __restrict__ Vt,
                                            f16* __restrict__ AO) {
  int bm = blockIdx.x, h = blockIdx.y;
  int m0 = bm * 128;
  const float* P = Sc + (size_t)h * S_LEN * S_LEN;
  const f16* B = Vt + (size_t)(h / NREP) * HD * S_LEN;
  __shared__ __align__(16) f16 As[128 * 32];
  __shared__ __align__(16) f16 Bs[128 * 32];
  f32x4 acc[4][4] = {};
  int t = threadIdx.x, lane = t & 63, w = t >> 6;
  int wm = (w >> 1) * 64, wn = (w & 1) * 64, lrow = lane & 15, quad = lane >> 4;
  int nkb = (bm + 1) * 4;  // causal: only t <= m0+127 contribute (rest of P is 0 anyway)
  for (int kb = 0; kb < nkb; ++kb) {
    // stage P tile fp32 -> f16
#pragma unroll
    for (int j = 0; j < 4; ++j) {
      int lin = t + 256 * j;  // 0..1023
      int row = lin >> 3, seg = lin & 7;
      float4 v = reinterpret_cast<const float4*>(P + (size_t)(m0 + row) * S_LEN + kb * 32)[seg];
      f16x4 o = {(f16)v.x, (f16)v.y, (f16)v.z, (f16)v.w};
      *reinterpret_cast<f16x4*>(As + row * 32 + seg * 4) = o;
    }
    stage16(B, S_LEN, 0, kb * 32, Bs);
    __syncthreads();
    mma_tile(As, Bs, acc, wm, wn, lrow, quad);
    __syncthreads();
  }
#pragma unroll
  for (int mi = 0; mi < 4; ++mi)
#pragma unroll
    for (int ni = 0; ni < 4; ++ni)
#pragma unroll
      for (int r = 0; r < 4; ++r) {
        int row = m0 + wm + mi * 16 + quad * 4 + r;
        int col = wn + ni * 16 + lrow;  // n0 == 0, N == 128
        AO[(size_t)row * HID + h * HD + col] = (f16)acc[mi][ni][r];
      }
}

// ---------------- launch ----------------
extern "C" void kernel_launch(void* const* d_in, const int* in_sizes, int n_in,
                              void* d_out, int out_size, void* d_ws, size_t ws_size,
                              hipStream_t stream) {
  const float* hs    = (const float*)d_in[0];
  const float* cosd  = (const float*)d_in[1];
  const float* sind  = (const float*)d_in[2];
  // d_in[3] = attention_mask (causal by construction; unused)
  const float* w_qkv = (const float*)d_in[4];
  const float* w_o   = (const float*)d_in[5];

  float* out  = (float*)d_out;
  float* attn = out + (size_t)S_LEN * HID;

  char* ws = (char*)d_ws;
  // ws layout (bytes, 256-aligned):
  f16* hs16   = (f16*)(ws + 0);          // 12,582,912 B ; reused later as AO
  f16* wq16   = (f16*)(ws + 12582912);   // 31,457,280 B ; reused later as Wo16
  f16* qkv16  = (f16*)(ws + 44040192);   // 20,971,520 B
  f16* Q16    = (f16*)(ws + 65011712);   // 12,582,912 B
  f16* K16    = (f16*)(ws + 77594624);   //  4,194,304 B
  f16* Vt16   = (f16*)(ws + 81788928);   //  4,194,304 B  (end: 85,983,232)
  f16* AO16   = hs16;
  f16* Wo16   = wq16;

  // 1-2: casts needed for QKV gemm
  k_cast4<<<6144, 256, 0, stream>>>(hs, hs16, (S_LEN * HID) / 4);
  k_cast4<<<15360, 256, 0, stream>>>(w_qkv, wq16, (OPSZ * HID) / 4);
  // 3: QKV projection
  k_gemm_qkv<<<dim3(40, 16), 256, 0, stream>>>(hs16, wq16, qkv16);
  // 4: RoPE -> Q, K
  k_rope<<<32768, 256, 0, stream>>>(qkv16, cosd, sind, Q16, K16);
  // 5: V transpose
  k_vt<<<dim3(64, 4, 8), 256, 0, stream>>>(qkv16, Vt16);
  // 6: cast w_o (after gemm_qkv; overwrites wq16 region)
  k_cast4<<<9216, 256, 0, stream>>>(w_o, Wo16, (HID * HID) / 4);
  // 7: scores into d_out attn region (raw, scaled, causal-zeroed)
  k_scores<<<dim3(16, 16, 24), 256, 0, stream>>>(Q16, K16, attn);
  // 8: softmax in place
  k_softmax<<<NH * S_LEN, 256, 0, stream>>>(attn);
  // 9: P @ V -> AO (f16)
  k_pv<<<dim3(16, 24), 256, 0, stream>>>(attn, Vt16, AO16);
  // 10: output projection -> d_out
  k_gemm_out<<<dim3(24, 16), 256, 0, stream>>>(AO16, Wo16, out);
}

// Round 2
// 933.080 us; speedup vs baseline: 1.0131x; 1.0131x over previous
//
#include <hip/hip_runtime.h>
#include <cstdint>
#include <cstddef>

#define S_LEN 2048
#define HID   3072
#define NH    24
#define NKV   8
#define HD    128
#define ROT   96
#define OPSZ  5120   // NH*HD + 2*NKV*HD
#define NREP  3      // NH/NKV
#define SCALING 0.08838834764831845f

typedef _Float16 f16;
typedef float f32x4 __attribute__((ext_vector_type(4)));
typedef _Float16 f16x8 __attribute__((ext_vector_type(8)));
typedef _Float16 f16x4 __attribute__((ext_vector_type(4)));

#define GLOBAL_AS __attribute__((address_space(1)))
#define LDS_AS    __attribute__((address_space(3)))

// ---------------- cast fp32 -> fp16 (4 elems/thread) ----------------
__global__ void k_cast4(const float* __restrict__ in, f16* __restrict__ out, int n4) {
  int i = blockIdx.x * blockDim.x + threadIdx.x;
  if (i >= n4) return;
  float4 v = reinterpret_cast<const float4*>(in)[i];
  f16x4 o = {(f16)v.x, (f16)v.y, (f16)v.z, (f16)v.w};
  reinterpret_cast<f16x4*>(out)[i] = o;
}

// ---------------- GEMM building blocks ----------------
// Async stage of a 128x32 f16 tile (rows m0.., cols k0..k0+31 of G, leading dim ld)
// into LDS [row][k] row-major (32 f16 = 64 B per row). 4 waves; each wave fills
// 16 contiguous rows = 1024 B per issue (wave-uniform LDS base + lane*16B). 2 issues.
__device__ __forceinline__ void stage_async(const f16* __restrict__ G, int ld, int m0, int k0,
                                            f16* __restrict__ Ls) {
  int t = threadIdx.x;
  int lane = t & 63, w = t >> 6;
#pragma unroll
  for (int j = 0; j < 2; ++j) {
    int rowBase = w * 16 + j * 64;            // wave-uniform
    int row = rowBase + (lane >> 2);
    int seg = lane & 3;
    const f16* gp = G + (size_t)(m0 + row) * ld + k0 + seg * 8;
    f16* lp = Ls + rowBase * 32;              // wave-uniform LDS base
    __builtin_amdgcn_global_load_lds((GLOBAL_AS const void*)gp, (LDS_AS void*)lp, 16, 0, 0);
  }
}

// One BK=32 step: 16 MFMAs on a 64x64 per-wave tile (4x4 of 16x16x32).
__device__ __forceinline__ void mma_tile(const f16* __restrict__ As, const f16* __restrict__ Bs,
                                         f32x4 acc[4][4], int wm, int wn, int lrow, int quad) {
  f16x8 a[4], b[4];
#pragma unroll
  for (int mi = 0; mi < 4; ++mi)
    a[mi] = *reinterpret_cast<const f16x8*>(As + (wm + mi * 16 + lrow) * 32 + quad * 8);
#pragma unroll
  for (int ni = 0; ni < 4; ++ni)
    b[ni] = *reinterpret_cast<const f16x8*>(Bs + (wn + ni * 16 + lrow) * 32 + quad * 8);
#pragma unroll
  for (int mi = 0; mi < 4; ++mi)
#pragma unroll
    for (int ni = 0; ni < 4; ++ni)
      acc[mi][ni] = __builtin_amdgcn_mfma_f32_16x16x32_f16(a[mi], b[ni], acc[mi][ni], 0, 0, 0);
}

// ---------------- QKV GEMM: C[2048,5120] = X[2048,3072] * W^T (W[5120,3072]) ----------------
__global__ __launch_bounds__(256) void k_gemm_qkv(const f16* __restrict__ A,
                                                  const f16* __restrict__ B,
                                                  f16* __restrict__ C) {
  int m0 = blockIdx.y * 128, n0 = blockIdx.x * 128;
  __shared__ __align__(16) f16 As[128 * 32];
  __shared__ __align__(16) f16 Bs[128 * 32];
  f32x4 acc[4][4] = {};
  int t = threadIdx.x, lane = t & 63, w = t >> 6;
  int wm = (w >> 1) * 64, wn = (w & 1) * 64, lrow = lane & 15, quad = lane >> 4;
  for (int kb = 0; kb < HID / 32; ++kb) {
    stage_async(A, HID, m0, kb * 32, As);
    stage_async(B, HID, n0, kb * 32, Bs);
    __syncthreads();
    mma_tile(As, Bs, acc, wm, wn, lrow, quad);
    __syncthreads();
  }
#pragma unroll
  for (int mi = 0; mi < 4; ++mi)
#pragma unroll
    for (int ni = 0; ni < 4; ++ni)
#pragma unroll
      for (int r = 0; r < 4; ++r) {
        int row = m0 + wm + mi * 16 + quad * 4 + r;
        int col = n0 + wn + ni * 16 + lrow;
        C[(size_t)row * OPSZ + col] = (f16)acc[mi][ni][r];
      }
}

// ---------------- out proj: Out[2048,3072] = AO[2048,3072] * Wo^T, fp32 out ----------------
__global__ __launch_bounds__(256) void k_gemm_out(const f16* __restrict__ A,
                                                  const f16* __restrict__ B,
                                                  float* __restrict__ C) {
  int m0 = blockIdx.y * 128, n0 = blockIdx.x * 128;
  __shared__ __align__(16) f16 As[128 * 32];
  __shared__ __align__(16) f16 Bs[128 * 32];
  f32x4 acc[4][4] = {};
  int t = threadIdx.x, lane = t & 63, w = t >> 6;
  int wm = (w >> 1) * 64, wn = (w & 1) * 64, lrow = lane & 15, quad = lane >> 4;
  for (int kb = 0; kb < HID / 32; ++kb) {
    stage_async(A, HID, m0, kb * 32, As);
    stage_async(B, HID, n0, kb * 32, Bs);
    __syncthreads();
    mma_tile(As, Bs, acc, wm, wn, lrow, quad);
    __syncthreads();
  }
#pragma unroll
  for (int mi = 0; mi < 4; ++mi)
#pragma unroll
    for (int ni = 0; ni < 4; ++ni)
#pragma unroll
      for (int r = 0; r < 4; ++r) {
        int row = m0 + wm + mi * 16 + quad * 4 + r;
        int col = n0 + wn + ni * 16 + lrow;
        C[(size_t)row * HID + col] = acc[mi][ni][r];
      }
}

// ---------------- RoPE on Q and K heads ----------------
// qkv[2048,5120] f16 -> Q[24,2048,128] f16, Kc[8,2048,128] f16
__global__ void k_rope(const f16* __restrict__ qkv, const float* __restrict__ cosd,
                       const float* __restrict__ sind, f16* __restrict__ Q,
                       f16* __restrict__ Kc) {
  int idx = blockIdx.x * 256 + threadIdx.x;  // 32*2048*128 total
  int d = idx & 127;
  int s = (idx >> 7) & (S_LEN - 1);
  int hh = idx >> 18;  // 0..31
  int srcCol = (hh < NH) ? hh * HD + d : HID + (hh - NH) * HD + d;
  float x = (float)qkv[(size_t)s * OPSZ + srcCol];
  float r;
  if (d < ROT) {
    float c = cosd[s * ROT + d], sn = sind[s * ROT + d];
    int pd = (d < 48) ? d + 48 : d - 48;
    float px = (float)qkv[(size_t)s * OPSZ + srcCol - d + pd];
    r = x * c + ((d < 48) ? -px : px) * sn;
  } else {
    r = x;
  }
  f16 o = (f16)r;
  if (hh < NH) Q[((size_t)hh * S_LEN + s) * HD + d] = o;
  else         Kc[((size_t)(hh - NH) * S_LEN + s) * HD + d] = o;
}

// ---------------- V transpose: Vt[8,128,2048] <- qkv[:, 4096 + kv*128 + d] ----------------
__global__ void k_vt(const f16* __restrict__ qkv, f16* __restrict__ Vt) {
  __shared__ f16 tile[32][33];
  int s0 = blockIdx.x * 32, d0 = blockIdx.y * 32, kv = blockIdx.z;
  int tx = threadIdx.x & 31, ty = threadIdx.x >> 5;  // 32 x 8
#pragma unroll
  for (int i = 0; i < 4; ++i)
    tile[ty + i * 8][tx] = qkv[(size_t)(s0 + ty + i * 8) * OPSZ + 4096 + kv * HD + d0 + tx];
  __syncthreads();
#pragma unroll
  for (int i = 0; i < 4; ++i)
    Vt[((size_t)kv * HD + d0 + ty + i * 8) * S_LEN + s0 + tx] = tile[tx][ty + i * 8];
}

// ---------------- scores: Sc[h,s,t] = scale * Q_h . K_kv, causal (upper = 0) ----------------
__global__ __launch_bounds__(256) void k_scores(const f16* __restrict__ Q,
                                                const f16* __restrict__ Kc,
                                                float* __restrict__ Sc) {
  int bn = blockIdx.x, bm = blockIdx.y, h = blockIdx.z;
  float* out = Sc + (size_t)h * S_LEN * S_LEN;
  int m0 = bm * 128, n0 = bn * 128;
  int t = threadIdx.x;
  if (bn > bm) {  // fully masked block: final value is exactly 0
    float4 z = {0.f, 0.f, 0.f, 0.f};
#pragma unroll
    for (int j = 0; j < 16; ++j) {
      int lin = t + 256 * j;  // 0..4095 float4 chunks
      int row = lin >> 5;
      int seg = lin & 31;
      reinterpret_cast<float4*>(out + (size_t)(m0 + row) * S_LEN + n0)[seg] = z;
    }
    return;
  }
  __shared__ __align__(16) f16 As[128 * 32];
  __shared__ __align__(16) f16 Bs[128 * 32];
  f32x4 acc[4][4] = {};
  const f16* Ah = Q + (size_t)h * S_LEN * HD;
  const f16* Bh = Kc + (size_t)(h / NREP) * S_LEN * HD;
  int lane = t & 63, w = t >> 6;
  int wm = (w >> 1) * 64, wn = (w & 1) * 64, lrow = lane & 15, quad = lane >> 4;
  for (int kb = 0; kb < HD / 32; ++kb) {
    stage_async(Ah, HD, m0, kb * 32, As);
    stage_async(Bh, HD, n0, kb * 32, Bs);
    __syncthreads();
    mma_tile(As, Bs, acc, wm, wn, lrow, quad);
    __syncthreads();
  }
#pragma unroll
  for (int mi = 0; mi < 4; ++mi)
#pragma unroll
    for (int ni = 0; ni < 4; ++ni)
#pragma unroll
      for (int r = 0; r < 4; ++r) {
        int row = m0 + wm + mi * 16 + quad * 4 + r;
        int col = n0 + wn + ni * 16 + lrow;
        float v = acc[mi][ni][r] * SCALING;
        if (col > row) v = 0.f;
        out[(size_t)row * S_LEN + col] = v;
      }
}

// ---------------- row softmax in place over first (r+1) elements ----------------
__global__ __launch_bounds__(256) void k_softmax(float* __restrict__ Sc) {
  int r = blockIdx.x & (S_LEN - 1);
  int h = blockIdx.x >> 11;
  float* row = Sc + ((size_t)h * S_LEN + r) * S_LEN;
  int n = r + 1;
  int t = threadIdx.x;
  float vals[8];
  int cnt = 0;
  float mx = -3.0e38f;
  for (int i = t; i < n; i += 256) {
    float v = row[i];
    vals[cnt++] = v;
    mx = fmaxf(mx, v);
  }
  __shared__ float red[4];
#pragma unroll
  for (int o = 32; o > 0; o >>= 1) mx = fmaxf(mx, __shfl_down(mx, o));
  if ((t & 63) == 0) red[t >> 6] = mx;
  __syncthreads();
  mx = fmaxf(fmaxf(red[0], red[1]), fmaxf(red[2], red[3]));
  __syncthreads();
  float sum = 0.f;
  for (int j = 0; j < cnt; ++j) {
    vals[j] = __expf(vals[j] - mx);
    sum += vals[j];
  }
#pragma unroll
  for (int o = 32; o > 0; o >>= 1) sum += __shfl_down(sum, o);
  if ((t & 63) == 0) red[t >> 6] = sum;
  __syncthreads();
  sum = red[0] + red[1] + red[2] + red[3];
  float inv = 1.0f / sum;
  cnt = 0;
  for (int i = t; i < n; i += 256) row[i] = vals[cnt++] * inv;
}

// ---------------- PV: AO[s, h*128+d] = sum_t P[h,s,t] * V[kv,t,d] ----------------
// P fp32 read from d_out attn region (staged to f16), B = Vt[kv][d][t].
__global__ __launch_bounds__(256) void k_pv(const float* __restrict__ Sc,
                                            const f16* __restrict__ Vt,
                                            f16* __restrict__ AO) {
  int bm = blockIdx.x, h = blockIdx.y;
  int m0 = bm * 128;
  const float* P = Sc + (size_t)h * S_LEN * S_LEN;
  const f16* B = Vt + (size_t)(h / NREP) * HD * S_LEN;
  __shared__ __align__(16) f16 As[128 * 32];
  __shared__ __align__(16) f16 Bs[128 * 32];
  f32x4 acc[4][4] = {};
  int t = threadIdx.x, lane = t & 63, w = t >> 6;
  int wm = (w >> 1) * 64, wn = (w & 1) * 64, lrow = lane & 15, quad = lane >> 4;
  int nkb = (bm + 1) * 4;  // causal: only t <= m0+127 contribute (rest of P is 0 anyway)
  for (int kb = 0; kb < nkb; ++kb) {
    // stage P tile fp32 -> f16 (manual: conversion needs VGPR round-trip)
#pragma unroll
    for (int j = 0; j < 4; ++j) {
      int lin = t + 256 * j;  // 0..1023
      int row = lin >> 3, seg = lin & 7;
      float4 v = reinterpret_cast<const float4*>(P + (size_t)(m0 + row) * S_LEN + kb * 32)[seg];
      f16x4 o = {(f16)v.x, (f16)v.y, (f16)v.z, (f16)v.w};
      *reinterpret_cast<f16x4*>(As + row * 32 + seg * 4) = o;
    }
    stage_async(B, S_LEN, 0, kb * 32, Bs);
    __syncthreads();
    mma_tile(As, Bs, acc, wm, wn, lrow, quad);
    __syncthreads();
  }
#pragma unroll
  for (int mi = 0; mi < 4; ++mi)
#pragma unroll
    for (int ni = 0; ni < 4; ++ni)
#pragma unroll
      for (int r = 0; r < 4; ++r) {
        int row = m0 + wm + mi * 16 + quad * 4 + r;
        int col = wn + ni * 16 + lrow;  // n0 == 0, N == 128
        AO[(size_t)row * HID + h * HD + col] = (f16)acc[mi][ni][r];
      }
}

// ---------------- launch ----------------
extern "C" void kernel_launch(void* const* d_in, const int* in_sizes, int n_in,
                              void* d_out, int out_size, void* d_ws, size_t ws_size,
                              hipStream_t stream) {
  const float* hs    = (const float*)d_in[0];
  const float* cosd  = (const float*)d_in[1];
  const float* sind  = (const float*)d_in[2];
  // d_in[3] = attention_mask (causal by construction; unused)
  const float* w_qkv = (const float*)d_in[4];
  const float* w_o   = (const float*)d_in[5];

  float* out  = (float*)d_out;
  float* attn = out + (size_t)S_LEN * HID;

  char* ws = (char*)d_ws;
  // ws layout (bytes, 256-aligned):
  f16* hs16   = (f16*)(ws + 0);          // 12,582,912 B ; reused later as AO
  f16* wq16   = (f16*)(ws + 12582912);   // 31,457,280 B ; reused later as Wo16
  f16* qkv16  = (f16*)(ws + 44040192);   // 20,971,520 B
  f16* Q16    = (f16*)(ws + 65011712);   // 12,582,912 B
  f16* K16    = (f16*)(ws + 77594624);   //  4,194,304 B
  f16* Vt16   = (f16*)(ws + 81788928);   //  4,194,304 B  (end: 85,983,232)
  f16* AO16   = hs16;
  f16* Wo16   = wq16;

  // 1-2: casts needed for QKV gemm
  k_cast4<<<6144, 256, 0, stream>>>(hs, hs16, (S_LEN * HID) / 4);
  k_cast4<<<15360, 256, 0, stream>>>(w_qkv, wq16, (OPSZ * HID) / 4);
  // 3: QKV projection
  k_gemm_qkv<<<dim3(40, 16), 256, 0, stream>>>(hs16, wq16, qkv16);
  // 4: RoPE -> Q, K
  k_rope<<<32768, 256, 0, stream>>>(qkv16, cosd, sind, Q16, K16);
  // 5: V transpose
  k_vt<<<dim3(64, 4, 8), 256, 0, stream>>>(qkv16, Vt16);
  // 6: cast w_o (after gemm_qkv; overwrites wq16 region)
  k_cast4<<<9216, 256, 0, stream>>>(w_o, Wo16, (HID * HID) / 4);
  // 7: scores into d_out attn region (raw, scaled, causal-zeroed)
  k_scores<<<dim3(16, 16, 24), 256, 0, stream>>>(Q16, K16, attn);
  // 8: softmax in place
  k_softmax<<<NH * S_LEN, 256, 0, stream>>>(attn);
  // 9: P @ V -> AO (f16)
  k_pv<<<dim3(16, 24), 256, 0, stream>>>(attn, Vt16, AO16);
  // 10: output projection -> d_out
  k_gemm_out<<<dim3(24, 16), 256, 0, stream>>>(AO16, Wo16, out);
}